// Round 4
// baseline (851.460 us; speedup 1.0000x reference)
//
#include <hip/hip_runtime.h>

typedef _Float16 half8 __attribute__((ext_vector_type(8)));
typedef _Float16 half4 __attribute__((ext_vector_type(4)));
typedef float f32x4 __attribute__((ext_vector_type(4)));

#define DIM 512
#define MEMSZ 1024
#define NPIX 4096
#define NT 128      // n-tile per block (halves panel traffic vs NT=64)
#define MC 128      // m-chunk for online softmax
#define NCHUNK 8

// xT swizzle (row stride 1024B): spreads 8 16B slots. Proven in R0.
#define SWZX(n) ((((n) ^ ((n) >> 3)) & 7) << 4)
// pT swizzle (row stride 256B = 16 slots): 4-bit XOR, bijective per row.
#define SWZP(n) (((n) & 15) << 4)

// prep: memory fp32 [512][1024] -> mem_h fp16 [512][1024] and memT_h fp16 [1024][512]
__global__ void prep_kernel(const float* __restrict__ mem, _Float16* __restrict__ mem_h,
                            _Float16* __restrict__ memT_h) {
    int idx = blockIdx.x * 256 + threadIdx.x;   // 0 .. 512*1024-1
    int c = idx >> 10, m = idx & 1023;
    float v = mem[idx];
    _Float16 h = (_Float16)v;
    mem_h[idx] = h;
    memT_h[m * DIM + c] = h;
}

// Flash-style fused kernel. THE WALL (R0/R2 evidence): per-block panel reads are
// a fixed 2 MB (memT for G1 + mem for G2) flowing at ~7 TB/s aggregate ->
// dur ~= nblocks * 2MB / 7TB/s. NT=128 halves nblocks to 512. Logits can't all
// live in regs at NT=128, so softmax goes online over 8 m-chunks of 128:
//   per chunk: G1 (chunk logits, 32 regs) -> running max/sum update + rescale
//   of out-accumulator -> p chunk to 32KB pT LDS -> G2 accumulate.
// R3 bug (absmax 7.5): G2's bA fragment was loaded once and never advanced in k
// -- fixed with the reload mirroring G1's.
__global__ __launch_bounds__(512)
void fused_kernel(const float* __restrict__ x, const _Float16* __restrict__ mem_h,
                  const _Float16* __restrict__ memT_h, float* __restrict__ out) {
    // LDS: [0,128K)      xT fp16 [128 n][512 c], stride 1024B, SWZX
    //      [128K,160K)   pT fp16 [128 n][128 m], stride 256B, SWZP (per chunk)
    //      red1/red2 f32[128][8] ALIASED at pT+0 / pT+4K (barrier-protected:
    //      red written after prev G2 done, fully read before pT overwrite)
    __shared__ char smem[163840];
    char* pTb = smem + 131072;
    float* red1 = (float*)(smem + 131072);
    float* red2 = (float*)(smem + 135168);

    const int tid  = threadIdx.x;
    const int lane = tid & 63;
    const int w    = tid >> 6;               // wave 0..7
    const int bidx = blockIdx.x;
    const int b    = bidx >> 5;              // batch
    const int n0   = (bidx & 31) * NT;       // column tile start

    // ---- stage x tile [512c][128n] -> xT LDS (fp32->fp16, 4x4 transpose) ----
    {
        const int nq = (tid & 31) * 4;       // n quad 0..124
        const int cq = (tid >> 5) * 4;       // c quad 0..60
        const float* xp = x + (size_t)b * DIM * NPIX + n0 + nq;
        #pragma unroll
        for (int it = 0; it < 8; ++it) {
            int c = cq + it * 64;
            f32x4 v[4];
            #pragma unroll
            for (int r = 0; r < 4; ++r)
                v[r] = __builtin_nontemporal_load(
                           (const f32x4*)(xp + (size_t)(c + r) * NPIX));
            #pragma unroll
            for (int i = 0; i < 4; ++i) {
                int n = nq + i;
                half4 h = { (_Float16)v[0][i], (_Float16)v[1][i],
                            (_Float16)v[2][i], (_Float16)v[3][i] };
                int byte = (n * 1024 + c * 2) ^ SWZX(n);
                *(half4*)(smem + byte) = h;
            }
        }
    }
    __syncthreads();

    const int kg   = (lane >> 4) * 8;
    const int ln15 = lane & 15;

    // persistent flash state
    f32x4 acc2[4][8];                        // out acc: wave owns c[w*64,+64) x n[128]
    #pragma unroll
    for (int ci = 0; ci < 4; ++ci)
        #pragma unroll
        for (int ni = 0; ni < 8; ++ni)
            acc2[ci][ni] = (f32x4){0.f, 0.f, 0.f, 0.f};
    float run_max[8], run_sum[8];
    #pragma unroll
    for (int ni = 0; ni < 8; ++ni) { run_max[ni] = -1e30f; run_sum[ni] = 0.f; }

    const _Float16* a1base = memT_h + (size_t)(w * 16 + ln15) * DIM + kg;
    const _Float16* a2base = mem_h + (size_t)(w * 64 + ln15) * MEMSZ + kg;

    #pragma unroll 1
    for (int mc = 0; mc < NCHUNK; ++mc) {
        const int mbase = mc * MC;

        // ---- G1: chunk logits[128m x 128n]; wave owns m [w*16,+16), all n ----
        f32x4 acc1[8];
        #pragma unroll
        for (int ni = 0; ni < 8; ++ni) acc1[ni] = (f32x4){0.f, 0.f, 0.f, 0.f};
        {
            const _Float16* ap = a1base + (size_t)mbase * DIM;
            half8 A[4], bA[4], bB[4];

            #define LD_BQ(dst, j, q)                                               \
                _Pragma("unroll")                                                  \
                for (int t = 0; t < 4; ++t) {                                      \
                    int n = ((q) * 4 + t) * 16 + ln15;                             \
                    int byte = (n * 1024 + ((j) * 32 + kg) * 2) ^ SWZX(n);         \
                    dst[t] = *(const half8*)(smem + byte);                         \
                }

            A[0] = *(const half8*)(ap + 0);
            A[1] = *(const half8*)(ap + 32);
            A[2] = *(const half8*)(ap + 64);
            A[3] = *(const half8*)(ap + 96);
            LD_BQ(bA, 0, 0)
            #pragma unroll
            for (int j = 0; j < 16; ++j) {
                LD_BQ(bB, j, 1)
                __builtin_amdgcn_s_setprio(1);
                #pragma unroll
                for (int t = 0; t < 4; ++t)
                    acc1[t] = __builtin_amdgcn_mfma_f32_16x16x32_f16(
                        A[j & 3], bA[t], acc1[t], 0, 0, 0);
                __builtin_amdgcn_s_setprio(0);
                if (j < 15) { LD_BQ(bA, j + 1, 0) }
                __builtin_amdgcn_s_setprio(1);
                #pragma unroll
                for (int t = 0; t < 4; ++t)
                    acc1[4 + t] = __builtin_amdgcn_mfma_f32_16x16x32_f16(
                        A[j & 3], bB[t], acc1[4 + t], 0, 0, 0);
                __builtin_amdgcn_s_setprio(0);
                if (j < 12)
                    A[j & 3] = *(const half8*)(ap + (j + 4) * 32);
            }
            #undef LD_BQ
        }

        // ---- online softmax update (cross-wave over 8 waves via red LDS) ----
        // C/D layout: col = ln15 (n), row = (lane>>4)*4 + r (m within 16)
        {
            float pm[8];
            #pragma unroll
            for (int ni = 0; ni < 8; ++ni) {
                float m0 = fmaxf(fmaxf(acc1[ni][0], acc1[ni][1]),
                                 fmaxf(acc1[ni][2], acc1[ni][3]));
                m0 = fmaxf(m0, __shfl_xor(m0, 16));
                m0 = fmaxf(m0, __shfl_xor(m0, 32));
                pm[ni] = m0;
            }
            if (lane < 16) {
                #pragma unroll
                for (int ni = 0; ni < 8; ++ni)
                    red1[(ni * 16 + lane) * 8 + w] = pm[ni];
            }
            __syncthreads();
            float nmax[8], f[8];
            #pragma unroll
            for (int ni = 0; ni < 8; ++ni) {
                const f32x4* rv = (const f32x4*)&red1[(ni * 16 + ln15) * 8];
                f32x4 v0 = rv[0], v1 = rv[1];
                float cm = fmaxf(fmaxf(fmaxf(v0[0], v0[1]), fmaxf(v0[2], v0[3])),
                                 fmaxf(fmaxf(v1[0], v1[1]), fmaxf(v1[2], v1[3])));
                nmax[ni] = fmaxf(run_max[ni], cm);
                f[ni] = __expf(run_max[ni] - nmax[ni]);
            }
            // rescale out accumulator + running sum
            #pragma unroll
            for (int ni = 0; ni < 8; ++ni) {
                #pragma unroll
                for (int ci = 0; ci < 4; ++ci) {
                    acc2[ci][ni][0] *= f[ni]; acc2[ci][ni][1] *= f[ni];
                    acc2[ci][ni][2] *= f[ni]; acc2[ci][ni][3] *= f[ni];
                }
                run_sum[ni] *= f[ni];
            }
            // p = exp(l - nmax), partial sums
            float ps[8];
            #pragma unroll
            for (int ni = 0; ni < 8; ++ni) {
                float s = 0.f;
                #pragma unroll
                for (int r = 0; r < 4; ++r) {
                    float e = __expf(acc1[ni][r] - nmax[ni]);
                    acc1[ni][r] = e;
                    s += e;
                }
                s += __shfl_xor(s, 16);
                s += __shfl_xor(s, 32);
                ps[ni] = s;
            }
            if (lane < 16) {
                #pragma unroll
                for (int ni = 0; ni < 8; ++ni)
                    red2[(ni * 16 + lane) * 8 + w] = ps[ni];
            }
            __syncthreads();
            #pragma unroll
            for (int ni = 0; ni < 8; ++ni) {
                const f32x4* rv = (const f32x4*)&red2[(ni * 16 + ln15) * 8];
                f32x4 v0 = rv[0], v1 = rv[1];
                float cs = ((v0[0] + v0[1]) + (v0[2] + v0[3])) +
                           ((v1[0] + v1[1]) + (v1[2] + v1[3]));
                run_sum[ni] += cs;
                run_max[ni] = nmax[ni];
            }
            __syncthreads();   // all red reads done before pT overwrites them
        }

        // ---- write p chunk (fp16) to pT [128n][128m], swizzled ----
        {
            const int mloc = w * 16 + (lane >> 4) * 4;
            #pragma unroll
            for (int ni = 0; ni < 8; ++ni) {
                int n = ni * 16 + ln15;
                half4 h = { (_Float16)acc1[ni][0], (_Float16)acc1[ni][1],
                            (_Float16)acc1[ni][2], (_Float16)acc1[ni][3] };
                int byte = (n * 256 + mloc * 2) ^ SWZP(n);
                *(half4*)(pTb + byte) = h;
            }
        }
        __syncthreads();

        // ---- G2: acc2 += mem[c][m-chunk] @ p; wave owns c [w*64,+64) ----
        {
            const _Float16* ap = a2base + mbase;
            half8 aD[2][4], bA[4], bB[4];

            #define LD_B2(dst, t0, q)                                              \
                _Pragma("unroll")                                                  \
                for (int t = 0; t < 4; ++t) {                                      \
                    int n = ((q) * 4 + t) * 16 + ln15;                             \
                    int byte = (n * 256 + ((t0) * 32 + kg) * 2) ^ SWZP(n);         \
                    dst[t] = *(const half8*)(pTb + byte);                          \
                }

            #pragma unroll
            for (int ci = 0; ci < 4; ++ci)
                aD[0][ci] = *(const half8*)(ap + (size_t)ci * 16 * MEMSZ);
            LD_B2(bA, 0, 0)
            #pragma unroll
            for (int t0 = 0; t0 < 4; ++t0) {
                LD_B2(bB, t0, 1)
                if (t0 < 3) {
                    #pragma unroll
                    for (int ci = 0; ci < 4; ++ci)
                        aD[(t0 + 1) & 1][ci] = *(const half8*)(
                            ap + (size_t)ci * 16 * MEMSZ + (t0 + 1) * 32);
                }
                __builtin_amdgcn_s_setprio(1);
                #pragma unroll
                for (int ci = 0; ci < 4; ++ci)
                    #pragma unroll
                    for (int t = 0; t < 4; ++t)
                        acc2[ci][t] = __builtin_amdgcn_mfma_f32_16x16x32_f16(
                            aD[t0 & 1][ci], bA[t], acc2[ci][t], 0, 0, 0);
                __builtin_amdgcn_s_setprio(0);
                if (t0 < 3) { LD_B2(bA, t0 + 1, 0) }   // R3 FIX: advance bA in k
                __builtin_amdgcn_s_setprio(1);
                #pragma unroll
                for (int ci = 0; ci < 4; ++ci)
                    #pragma unroll
                    for (int t = 0; t < 4; ++t)
                        acc2[ci][4 + t] = __builtin_amdgcn_mfma_f32_16x16x32_f16(
                            aD[t0 & 1][ci], bB[t], acc2[ci][4 + t], 0, 0, 0);
                __builtin_amdgcn_s_setprio(0);
            }
            #undef LD_B2
        }
        __syncthreads();   // pT consumed; next chunk may overwrite red/pT
    }

    // ---- epilogue: normalize by 1/run_sum and store (non-temporal) ----
    {
        float rinv[8];
        #pragma unroll
        for (int ni = 0; ni < 8; ++ni) rinv[ni] = 1.f / run_sum[ni];
        #pragma unroll
        for (int ci = 0; ci < 4; ++ci) {
            #pragma unroll
            for (int ni = 0; ni < 8; ++ni) {
                int c = w * 64 + ci * 16 + (lane >> 4) * 4;
                int n = n0 + ni * 16 + ln15;
                float* op = out + (size_t)(b * DIM + c) * NPIX + n;
                #pragma unroll
                for (int r = 0; r < 4; ++r)
                    __builtin_nontemporal_store(acc2[ci][ni][r] * rinv[ni],
                                                op + (size_t)r * NPIX);
            }
        }
    }
}

extern "C" void kernel_launch(void* const* d_in, const int* in_sizes, int n_in,
                              void* d_out, int out_size, void* d_ws, size_t ws_size,
                              hipStream_t stream) {
    const float* x   = (const float*)d_in[0];
    const float* mem = (const float*)d_in[1];
    float* out = (float*)d_out;

    _Float16* mem_h  = (_Float16*)d_ws;                  // [512][1024] fp16, 1 MB
    _Float16* memT_h = mem_h + (size_t)DIM * MEMSZ;      // [1024][512] fp16, 1 MB

    prep_kernel<<<2048, 256, 0, stream>>>(mem, mem_h, memT_h);
    fused_kernel<<<16 * 32, 512, 0, stream>>>(x, mem_h, memT_h, out);
}

// Round 5
// 849.995 us; speedup vs baseline: 1.0017x; 1.0017x over previous
//
#include <hip/hip_runtime.h>

typedef _Float16 half8 __attribute__((ext_vector_type(8)));
typedef _Float16 half4 __attribute__((ext_vector_type(4)));
typedef float f32x4 __attribute__((ext_vector_type(4)));

#define DIM 512
#define MEMSZ 1024
#define NPIX 4096
#define NT 128      // n-tile per block (halves panel traffic vs NT=64)
#define MC 128      // m-chunk for online softmax
#define NCHUNK 8

// xT swizzle (row stride 1024B): spreads 8 16B slots. Proven in R0.
#define SWZX(n) ((((n) ^ ((n) >> 3)) & 7) << 4)
// pT swizzle (row stride 256B = 16 slots): 4-bit XOR, bijective per row.
#define SWZP(n) (((n) & 15) << 4)

// prep: memory fp32 [512][1024] -> mem_h fp16 [512][1024] and memT_h fp16 [1024][512]
__global__ void prep_kernel(const float* __restrict__ mem, _Float16* __restrict__ mem_h,
                            _Float16* __restrict__ memT_h) {
    int idx = blockIdx.x * 256 + threadIdx.x;   // 0 .. 512*1024-1
    int c = idx >> 10, m = idx & 1023;
    float v = mem[idx];
    _Float16 h = (_Float16)v;
    mem_h[idx] = h;
    memT_h[m * DIM + c] = h;
}

// Flash-style fused kernel (structure proven correct in R4, absmax 0.043).
// R4 failure: __launch_bounds__(512) let the compiler target 4 waves/SIMD
// (128 VGPRs) even though 160KB LDS caps the CU at 1 block = 2 waves/SIMD.
// Register demand is ~240 (acc2 128 + acc1 32 + frags 48 + state/addr 30), so
// acc2 spilled to scratch: FETCH 718 MB, MfmaUtil 6.5%, 851 us.
// FIX: __launch_bounds__(512, 2) -- min 2 waves/EU -> 256-reg budget, no spill.
__global__ __launch_bounds__(512, 2)
void fused_kernel(const float* __restrict__ x, const _Float16* __restrict__ mem_h,
                  const _Float16* __restrict__ memT_h, float* __restrict__ out) {
    // LDS: [0,128K)      xT fp16 [128 n][512 c], stride 1024B, SWZX
    //      [128K,160K)   pT fp16 [128 n][128 m], stride 256B, SWZP (per chunk)
    //      red1/red2 f32[128][8] ALIASED at pT+0 / pT+4K (barrier-protected:
    //      red written after prev G2 done, fully read before pT overwrite)
    __shared__ char smem[163840];
    char* pTb = smem + 131072;
    float* red1 = (float*)(smem + 131072);
    float* red2 = (float*)(smem + 135168);

    const int tid  = threadIdx.x;
    const int lane = tid & 63;
    const int w    = tid >> 6;               // wave 0..7
    const int bidx = blockIdx.x;
    const int b    = bidx >> 5;              // batch
    const int n0   = (bidx & 31) * NT;       // column tile start

    // ---- stage x tile [512c][128n] -> xT LDS (fp32->fp16, 4x4 transpose) ----
    {
        const int nq = (tid & 31) * 4;       // n quad 0..124
        const int cq = (tid >> 5) * 4;       // c quad 0..60
        const float* xp = x + (size_t)b * DIM * NPIX + n0 + nq;
        #pragma unroll
        for (int it = 0; it < 8; ++it) {
            int c = cq + it * 64;
            f32x4 v[4];
            #pragma unroll
            for (int r = 0; r < 4; ++r)
                v[r] = __builtin_nontemporal_load(
                           (const f32x4*)(xp + (size_t)(c + r) * NPIX));
            #pragma unroll
            for (int i = 0; i < 4; ++i) {
                int n = nq + i;
                half4 h = { (_Float16)v[0][i], (_Float16)v[1][i],
                            (_Float16)v[2][i], (_Float16)v[3][i] };
                int byte = (n * 1024 + c * 2) ^ SWZX(n);
                *(half4*)(smem + byte) = h;
            }
        }
    }
    __syncthreads();

    const int kg   = (lane >> 4) * 8;
    const int ln15 = lane & 15;

    // persistent flash state
    f32x4 acc2[4][8];                        // out acc: wave owns c[w*64,+64) x n[128]
    #pragma unroll
    for (int ci = 0; ci < 4; ++ci)
        #pragma unroll
        for (int ni = 0; ni < 8; ++ni)
            acc2[ci][ni] = (f32x4){0.f, 0.f, 0.f, 0.f};
    float run_max[8], run_sum[8];
    #pragma unroll
    for (int ni = 0; ni < 8; ++ni) { run_max[ni] = -1e30f; run_sum[ni] = 0.f; }

    const _Float16* a1base = memT_h + (size_t)(w * 16 + ln15) * DIM + kg;
    const _Float16* a2base = mem_h + (size_t)(w * 64 + ln15) * MEMSZ + kg;

    #pragma unroll 1
    for (int mc = 0; mc < NCHUNK; ++mc) {
        const int mbase = mc * MC;

        // ---- G1: chunk logits[128m x 128n]; wave owns m [w*16,+16), all n ----
        f32x4 acc1[8];
        #pragma unroll
        for (int ni = 0; ni < 8; ++ni) acc1[ni] = (f32x4){0.f, 0.f, 0.f, 0.f};
        {
            const _Float16* ap = a1base + (size_t)mbase * DIM;
            half8 A[4], bA[4], bB[4];

            #define LD_BQ(dst, j, q)                                               \
                _Pragma("unroll")                                                  \
                for (int t = 0; t < 4; ++t) {                                      \
                    int n = ((q) * 4 + t) * 16 + ln15;                             \
                    int byte = (n * 1024 + ((j) * 32 + kg) * 2) ^ SWZX(n);         \
                    dst[t] = *(const half8*)(smem + byte);                         \
                }

            A[0] = *(const half8*)(ap + 0);
            A[1] = *(const half8*)(ap + 32);
            A[2] = *(const half8*)(ap + 64);
            A[3] = *(const half8*)(ap + 96);
            LD_BQ(bA, 0, 0)
            #pragma unroll
            for (int j = 0; j < 16; ++j) {
                LD_BQ(bB, j, 1)
                __builtin_amdgcn_s_setprio(1);
                #pragma unroll
                for (int t = 0; t < 4; ++t)
                    acc1[t] = __builtin_amdgcn_mfma_f32_16x16x32_f16(
                        A[j & 3], bA[t], acc1[t], 0, 0, 0);
                __builtin_amdgcn_s_setprio(0);
                if (j < 15) { LD_BQ(bA, j + 1, 0) }
                __builtin_amdgcn_s_setprio(1);
                #pragma unroll
                for (int t = 0; t < 4; ++t)
                    acc1[4 + t] = __builtin_amdgcn_mfma_f32_16x16x32_f16(
                        A[j & 3], bB[t], acc1[4 + t], 0, 0, 0);
                __builtin_amdgcn_s_setprio(0);
                if (j < 12)
                    A[j & 3] = *(const half8*)(ap + (j + 4) * 32);
            }
            #undef LD_BQ
        }

        // ---- online softmax update (cross-wave over 8 waves via red LDS) ----
        // C/D layout: col = ln15 (n), row = (lane>>4)*4 + r (m within 16)
        {
            float pm[8];
            #pragma unroll
            for (int ni = 0; ni < 8; ++ni) {
                float m0 = fmaxf(fmaxf(acc1[ni][0], acc1[ni][1]),
                                 fmaxf(acc1[ni][2], acc1[ni][3]));
                m0 = fmaxf(m0, __shfl_xor(m0, 16));
                m0 = fmaxf(m0, __shfl_xor(m0, 32));
                pm[ni] = m0;
            }
            if (lane < 16) {
                #pragma unroll
                for (int ni = 0; ni < 8; ++ni)
                    red1[(ni * 16 + lane) * 8 + w] = pm[ni];
            }
            __syncthreads();
            float nmax[8], f[8];
            #pragma unroll
            for (int ni = 0; ni < 8; ++ni) {
                const f32x4* rv = (const f32x4*)&red1[(ni * 16 + ln15) * 8];
                f32x4 v0 = rv[0], v1 = rv[1];
                float cm = fmaxf(fmaxf(fmaxf(v0[0], v0[1]), fmaxf(v0[2], v0[3])),
                                 fmaxf(fmaxf(v1[0], v1[1]), fmaxf(v1[2], v1[3])));
                nmax[ni] = fmaxf(run_max[ni], cm);
                f[ni] = __expf(run_max[ni] - nmax[ni]);
            }
            // rescale out accumulator + running sum
            #pragma unroll
            for (int ni = 0; ni < 8; ++ni) {
                #pragma unroll
                for (int ci = 0; ci < 4; ++ci) {
                    acc2[ci][ni][0] *= f[ni]; acc2[ci][ni][1] *= f[ni];
                    acc2[ci][ni][2] *= f[ni]; acc2[ci][ni][3] *= f[ni];
                }
                run_sum[ni] *= f[ni];
            }
            // p = exp(l - nmax), partial sums
            float ps[8];
            #pragma unroll
            for (int ni = 0; ni < 8; ++ni) {
                float s = 0.f;
                #pragma unroll
                for (int r = 0; r < 4; ++r) {
                    float e = __expf(acc1[ni][r] - nmax[ni]);
                    acc1[ni][r] = e;
                    s += e;
                }
                s += __shfl_xor(s, 16);
                s += __shfl_xor(s, 32);
                ps[ni] = s;
            }
            if (lane < 16) {
                #pragma unroll
                for (int ni = 0; ni < 8; ++ni)
                    red2[(ni * 16 + lane) * 8 + w] = ps[ni];
            }
            __syncthreads();
            #pragma unroll
            for (int ni = 0; ni < 8; ++ni) {
                const f32x4* rv = (const f32x4*)&red2[(ni * 16 + ln15) * 8];
                f32x4 v0 = rv[0], v1 = rv[1];
                float cs = ((v0[0] + v0[1]) + (v0[2] + v0[3])) +
                           ((v1[0] + v1[1]) + (v1[2] + v1[3]));
                run_sum[ni] += cs;
                run_max[ni] = nmax[ni];
            }
            __syncthreads();   // all red reads done before pT overwrites them
        }

        // ---- write p chunk (fp16) to pT [128n][128m], swizzled ----
        {
            const int mloc = w * 16 + (lane >> 4) * 4;
            #pragma unroll
            for (int ni = 0; ni < 8; ++ni) {
                int n = ni * 16 + ln15;
                half4 h = { (_Float16)acc1[ni][0], (_Float16)acc1[ni][1],
                            (_Float16)acc1[ni][2], (_Float16)acc1[ni][3] };
                int byte = (n * 256 + mloc * 2) ^ SWZP(n);
                *(half4*)(pTb + byte) = h;
            }
        }
        __syncthreads();

        // ---- G2: acc2 += mem[c][m-chunk] @ p; wave owns c [w*64,+64) ----
        {
            const _Float16* ap = a2base + mbase;
            half8 aD[2][4], bA[4], bB[4];

            #define LD_B2(dst, t0, q)                                              \
                _Pragma("unroll")                                                  \
                for (int t = 0; t < 4; ++t) {                                      \
                    int n = ((q) * 4 + t) * 16 + ln15;                             \
                    int byte = (n * 256 + ((t0) * 32 + kg) * 2) ^ SWZP(n);         \
                    dst[t] = *(const half8*)(pTb + byte);                          \
                }

            #pragma unroll
            for (int ci = 0; ci < 4; ++ci)
                aD[0][ci] = *(const half8*)(ap + (size_t)ci * 16 * MEMSZ);
            LD_B2(bA, 0, 0)
            #pragma unroll
            for (int t0 = 0; t0 < 4; ++t0) {
                LD_B2(bB, t0, 1)
                if (t0 < 3) {
                    #pragma unroll
                    for (int ci = 0; ci < 4; ++ci)
                        aD[(t0 + 1) & 1][ci] = *(const half8*)(
                            ap + (size_t)ci * 16 * MEMSZ + (t0 + 1) * 32);
                }
                __builtin_amdgcn_s_setprio(1);
                #pragma unroll
                for (int ci = 0; ci < 4; ++ci)
                    #pragma unroll
                    for (int t = 0; t < 4; ++t)
                        acc2[ci][t] = __builtin_amdgcn_mfma_f32_16x16x32_f16(
                            aD[t0 & 1][ci], bA[t], acc2[ci][t], 0, 0, 0);
                __builtin_amdgcn_s_setprio(0);
                if (t0 < 3) { LD_B2(bA, t0 + 1, 0) }   // advance bA in k
                __builtin_amdgcn_s_setprio(1);
                #pragma unroll
                for (int ci = 0; ci < 4; ++ci)
                    #pragma unroll
                    for (int t = 0; t < 4; ++t)
                        acc2[ci][4 + t] = __builtin_amdgcn_mfma_f32_16x16x32_f16(
                            aD[t0 & 1][ci], bB[t], acc2[ci][4 + t], 0, 0, 0);
                __builtin_amdgcn_s_setprio(0);
            }
            #undef LD_B2
        }
        __syncthreads();   // pT consumed; next chunk may overwrite red/pT
    }

    // ---- epilogue: normalize by 1/run_sum and store (non-temporal) ----
    {
        float rinv[8];
        #pragma unroll
        for (int ni = 0; ni < 8; ++ni) rinv[ni] = 1.f / run_sum[ni];
        #pragma unroll
        for (int ci = 0; ci < 4; ++ci) {
            #pragma unroll
            for (int ni = 0; ni < 8; ++ni) {
                int c = w * 64 + ci * 16 + (lane >> 4) * 4;
                int n = n0 + ni * 16 + ln15;
                float* op = out + (size_t)(b * DIM + c) * NPIX + n;
                #pragma unroll
                for (int r = 0; r < 4; ++r)
                    __builtin_nontemporal_store(acc2[ci][ni][r] * rinv[ni],
                                                op + (size_t)r * NPIX);
            }
        }
    }
}

extern "C" void kernel_launch(void* const* d_in, const int* in_sizes, int n_in,
                              void* d_out, int out_size, void* d_ws, size_t ws_size,
                              hipStream_t stream) {
    const float* x   = (const float*)d_in[0];
    const float* mem = (const float*)d_in[1];
    float* out = (float*)d_out;

    _Float16* mem_h  = (_Float16*)d_ws;                  // [512][1024] fp16, 1 MB
    _Float16* memT_h = mem_h + (size_t)DIM * MEMSZ;      // [1024][512] fp16, 1 MB

    prep_kernel<<<2048, 256, 0, stream>>>(mem, mem_h, memT_h);
    fused_kernel<<<16 * 32, 512, 0, stream>>>(x, mem_h, memT_h, out);
}

// Round 6
// 580.434 us; speedup vs baseline: 1.4669x; 1.4644x over previous
//
#include <hip/hip_runtime.h>

typedef _Float16 half8 __attribute__((ext_vector_type(8)));
typedef _Float16 half4 __attribute__((ext_vector_type(4)));
typedef float f32x4 __attribute__((ext_vector_type(4)));

#define DIM 512
#define MEMSZ 1024
#define NPIX 4096
#define NT 128      // n-tile per block (halves panel traffic vs NT=64)
#define MC 128      // m-chunk for online softmax
#define NCHUNK 8

// xT swizzle (row stride 1024B): spreads 8 16B slots. Proven in R0.
#define SWZX(n) ((((n) ^ ((n) >> 3)) & 7) << 4)
// pT swizzle (row stride 256B = 16 slots): 4-bit XOR, bijective per row.
#define SWZP(n) (((n) & 15) << 4)

// prep: memory fp32 [512][1024] -> mem_h fp16 [512][1024] and memT_h fp16 [1024][512]
__global__ void prep_kernel(const float* __restrict__ mem, _Float16* __restrict__ mem_h,
                            _Float16* __restrict__ memT_h) {
    int idx = blockIdx.x * 256 + threadIdx.x;   // 0 .. 512*1024-1
    int c = idx >> 10, m = idx & 1023;
    float v = mem[idx];
    _Float16 h = (_Float16)v;
    mem_h[idx] = h;
    memT_h[m * DIM + c] = h;
}

// Flash-style fused kernel (structure correct since R4, absmax 0.043).
// R4/R5 failure: allocator spilled acc2 (FETCH 718MB, MfmaUtil 6.5%) and both
// launch_bounds variants produced identical binaries. FIX: pin register classes
// via inline-asm MFMA constraints -- acc2 (128 regs) forced into AGPRs ("+a"),
// acc1 (32) forced into arch VGPRs ("+v"). Arch demand ~115 <= 128, AGPR = 128,
// total 256/wave = 2 waves/SIMD (the LDS-imposed cap). This reproduces R0's
// clean 128V+128A allocation on the flash structure.
__global__ __launch_bounds__(512, 2)
void fused_kernel(const float* __restrict__ x, const _Float16* __restrict__ mem_h,
                  const _Float16* __restrict__ memT_h, float* __restrict__ out) {
    // LDS: [0,128K)      xT fp16 [128 n][512 c], stride 1024B, SWZX
    //      [128K,160K)   pT fp16 [128 n][128 m], stride 256B, SWZP (per chunk)
    //      red1/red2 f32[128][8] ALIASED at pT+0 / pT+4K (barrier-protected:
    //      red written after prev G2 done, fully read before pT overwrite)
    __shared__ char smem[163840];
    char* pTb = smem + 131072;
    float* red1 = (float*)(smem + 131072);
    float* red2 = (float*)(smem + 135168);

    const int tid  = threadIdx.x;
    const int lane = tid & 63;
    const int w    = tid >> 6;               // wave 0..7
    const int bidx = blockIdx.x;
    const int b    = bidx >> 5;              // batch
    const int n0   = (bidx & 31) * NT;       // column tile start

    // ---- stage x tile [512c][128n] -> xT LDS (fp32->fp16, 4x4 transpose) ----
    {
        const int nq = (tid & 31) * 4;       // n quad 0..124
        const int cq = (tid >> 5) * 4;       // c quad 0..60
        const float* xp = x + (size_t)b * DIM * NPIX + n0 + nq;
        #pragma unroll
        for (int it = 0; it < 8; ++it) {
            int c = cq + it * 64;
            f32x4 v[4];
            #pragma unroll
            for (int r = 0; r < 4; ++r)
                v[r] = __builtin_nontemporal_load(
                           (const f32x4*)(xp + (size_t)(c + r) * NPIX));
            #pragma unroll
            for (int i = 0; i < 4; ++i) {
                int n = nq + i;
                half4 h = { (_Float16)v[0][i], (_Float16)v[1][i],
                            (_Float16)v[2][i], (_Float16)v[3][i] };
                int byte = (n * 1024 + c * 2) ^ SWZX(n);
                *(half4*)(smem + byte) = h;
            }
        }
    }
    __syncthreads();

    const int kg   = (lane >> 4) * 8;
    const int ln15 = lane & 15;

    // persistent flash state: acc2 pinned to AGPRs via asm constraints below
    f32x4 acc2[4][8];                        // out acc: wave owns c[w*64,+64) x n[128]
    #pragma unroll
    for (int ci = 0; ci < 4; ++ci)
        #pragma unroll
        for (int ni = 0; ni < 8; ++ni)
            acc2[ci][ni] = (f32x4){0.f, 0.f, 0.f, 0.f};
    float run_max[8], run_sum[8];
    #pragma unroll
    for (int ni = 0; ni < 8; ++ni) { run_max[ni] = -1e30f; run_sum[ni] = 0.f; }

    const _Float16* a1base = memT_h + (size_t)(w * 16 + ln15) * DIM + kg;
    const _Float16* a2base = mem_h + (size_t)(w * 64 + ln15) * MEMSZ + kg;

    #pragma unroll 1
    for (int mc = 0; mc < NCHUNK; ++mc) {
        const int mbase = mc * MC;

        // ---- G1: chunk logits[128m x 128n]; wave owns m [w*16,+16), all n ----
        f32x4 acc1[8];
        #pragma unroll
        for (int ni = 0; ni < 8; ++ni) acc1[ni] = (f32x4){0.f, 0.f, 0.f, 0.f};
        {
            const _Float16* ap = a1base + (size_t)mbase * DIM;
            half8 A[4], bA[4], bB[4];

            #define LD_BQ(dst, j, q)                                               \
                _Pragma("unroll")                                                  \
                for (int t = 0; t < 4; ++t) {                                      \
                    int n = ((q) * 4 + t) * 16 + ln15;                             \
                    int byte = (n * 1024 + ((j) * 32 + kg) * 2) ^ SWZX(n);         \
                    dst[t] = *(const half8*)(smem + byte);                         \
                }
            // acc1 pinned to arch VGPRs: "+v"
            #define MFMA1G(afrag, bfr, off)                                        \
                __builtin_amdgcn_s_setprio(1);                                     \
                _Pragma("unroll")                                                  \
                for (int t = 0; t < 4; ++t)                                        \
                    asm("v_mfma_f32_16x16x32_f16 %0, %1, %2, %0"                   \
                        : "+v"(acc1[(off) + t]) : "v"(afrag), "v"(bfr[t]));        \
                __builtin_amdgcn_s_setprio(0);

            A[0] = *(const half8*)(ap + 0);
            A[1] = *(const half8*)(ap + 32);
            A[2] = *(const half8*)(ap + 64);
            A[3] = *(const half8*)(ap + 96);
            LD_BQ(bA, 0, 0)
            #pragma unroll
            for (int j = 0; j < 16; ++j) {
                LD_BQ(bB, j, 1)
                MFMA1G(A[j & 3], bA, 0)
                if (j < 15) { LD_BQ(bA, j + 1, 0) }
                MFMA1G(A[j & 3], bB, 4)
                if (j < 12)
                    A[j & 3] = *(const half8*)(ap + (j + 4) * 32);
            }
            #undef LD_BQ
            #undef MFMA1G
        }
        // hazard guard: inline-asm MFMA is opaque to the compiler's hazard
        // pass; give the XDL pipe time before VALU reads acc1.
        asm volatile("s_nop 7\n\ts_nop 7");

        // ---- online softmax update (cross-wave over 8 waves via red LDS) ----
        // C/D layout: col = ln15 (n), row = (lane>>4)*4 + r (m within 16)
        {
            float pm[8];
            #pragma unroll
            for (int ni = 0; ni < 8; ++ni) {
                float m0 = fmaxf(fmaxf(acc1[ni][0], acc1[ni][1]),
                                 fmaxf(acc1[ni][2], acc1[ni][3]));
                m0 = fmaxf(m0, __shfl_xor(m0, 16));
                m0 = fmaxf(m0, __shfl_xor(m0, 32));
                pm[ni] = m0;
            }
            if (lane < 16) {
                #pragma unroll
                for (int ni = 0; ni < 8; ++ni)
                    red1[(ni * 16 + lane) * 8 + w] = pm[ni];
            }
            __syncthreads();
            float nmax[8], f[8];
            #pragma unroll
            for (int ni = 0; ni < 8; ++ni) {
                const f32x4* rv = (const f32x4*)&red1[(ni * 16 + ln15) * 8];
                f32x4 v0 = rv[0], v1 = rv[1];
                float cm = fmaxf(fmaxf(fmaxf(v0[0], v0[1]), fmaxf(v0[2], v0[3])),
                                 fmaxf(fmaxf(v1[0], v1[1]), fmaxf(v1[2], v1[3])));
                nmax[ni] = fmaxf(run_max[ni], cm);
                f[ni] = __expf(run_max[ni] - nmax[ni]);
            }
            // rescale out accumulator + running sum (accvgpr_read/write traffic,
            // ~384 VALU per chunk -- negligible)
            #pragma unroll
            for (int ni = 0; ni < 8; ++ni) {
                #pragma unroll
                for (int ci = 0; ci < 4; ++ci) {
                    acc2[ci][ni][0] *= f[ni]; acc2[ci][ni][1] *= f[ni];
                    acc2[ci][ni][2] *= f[ni]; acc2[ci][ni][3] *= f[ni];
                }
                run_sum[ni] *= f[ni];
            }
            // p = exp(l - nmax), partial sums
            float ps[8];
            #pragma unroll
            for (int ni = 0; ni < 8; ++ni) {
                float s = 0.f;
                #pragma unroll
                for (int r = 0; r < 4; ++r) {
                    float e = __expf(acc1[ni][r] - nmax[ni]);
                    acc1[ni][r] = e;
                    s += e;
                }
                s += __shfl_xor(s, 16);
                s += __shfl_xor(s, 32);
                ps[ni] = s;
            }
            if (lane < 16) {
                #pragma unroll
                for (int ni = 0; ni < 8; ++ni)
                    red2[(ni * 16 + lane) * 8 + w] = ps[ni];
            }
            __syncthreads();
            #pragma unroll
            for (int ni = 0; ni < 8; ++ni) {
                const f32x4* rv = (const f32x4*)&red2[(ni * 16 + ln15) * 8];
                f32x4 v0 = rv[0], v1 = rv[1];
                float cs = ((v0[0] + v0[1]) + (v0[2] + v0[3])) +
                           ((v1[0] + v1[1]) + (v1[2] + v1[3]));
                run_sum[ni] += cs;
                run_max[ni] = nmax[ni];
            }
            __syncthreads();   // all red reads done before pT overwrites them
        }

        // ---- write p chunk (fp16) to pT [128n][128m], swizzled ----
        {
            const int mloc = w * 16 + (lane >> 4) * 4;
            #pragma unroll
            for (int ni = 0; ni < 8; ++ni) {
                int n = ni * 16 + ln15;
                half4 h = { (_Float16)acc1[ni][0], (_Float16)acc1[ni][1],
                            (_Float16)acc1[ni][2], (_Float16)acc1[ni][3] };
                int byte = (n * 256 + mloc * 2) ^ SWZP(n);
                *(half4*)(pTb + byte) = h;
            }
        }
        __syncthreads();

        // ---- G2: acc2 += mem[c][m-chunk] @ p; wave owns c [w*64,+64) ----
        {
            const _Float16* ap = a2base + mbase;
            half8 aD[2][4], bA[4], bB[4];

            #define LD_B2(dst, t0, q)                                              \
                _Pragma("unroll")                                                  \
                for (int t = 0; t < 4; ++t) {                                      \
                    int n = ((q) * 4 + t) * 16 + ln15;                             \
                    int byte = (n * 256 + ((t0) * 32 + kg) * 2) ^ SWZP(n);         \
                    dst[t] = *(const half8*)(pTb + byte);                          \
                }
            // acc2 pinned to AGPRs: "+a"
            #define MFMA2G(buf, bfr, off)                                          \
                __builtin_amdgcn_s_setprio(1);                                     \
                _Pragma("unroll")                                                  \
                for (int ci = 0; ci < 4; ++ci)                                     \
                    _Pragma("unroll")                                              \
                    for (int t = 0; t < 4; ++t)                                    \
                        asm("v_mfma_f32_16x16x32_f16 %0, %1, %2, %0"               \
                            : "+a"(acc2[ci][(off) + t])                            \
                            : "v"(aD[buf][ci]), "v"(bfr[t]));                      \
                __builtin_amdgcn_s_setprio(0);

            #pragma unroll
            for (int ci = 0; ci < 4; ++ci)
                aD[0][ci] = *(const half8*)(ap + (size_t)ci * 16 * MEMSZ);
            LD_B2(bA, 0, 0)
            #pragma unroll
            for (int t0 = 0; t0 < 4; ++t0) {
                LD_B2(bB, t0, 1)
                if (t0 < 3) {
                    #pragma unroll
                    for (int ci = 0; ci < 4; ++ci)
                        aD[(t0 + 1) & 1][ci] = *(const half8*)(
                            ap + (size_t)ci * 16 * MEMSZ + (t0 + 1) * 32);
                }
                MFMA2G(t0 & 1, bA, 0)
                if (t0 < 3) { LD_B2(bA, t0 + 1, 0) }   // advance bA in k
                MFMA2G(t0 & 1, bB, 4)
            }
            #undef LD_B2
            #undef MFMA2G
        }
        __syncthreads();   // pT consumed; next chunk may overwrite red/pT
    }

    // ---- epilogue: normalize by 1/run_sum and store (non-temporal) ----
    {
        float rinv[8];
        #pragma unroll
        for (int ni = 0; ni < 8; ++ni) rinv[ni] = 1.f / run_sum[ni];
        #pragma unroll
        for (int ci = 0; ci < 4; ++ci) {
            #pragma unroll
            for (int ni = 0; ni < 8; ++ni) {
                int c = w * 64 + ci * 16 + (lane >> 4) * 4;
                int n = n0 + ni * 16 + ln15;
                float* op = out + (size_t)(b * DIM + c) * NPIX + n;
                #pragma unroll
                for (int r = 0; r < 4; ++r)
                    __builtin_nontemporal_store(acc2[ci][ni][r] * rinv[ni],
                                                op + (size_t)r * NPIX);
            }
        }
    }
}

extern "C" void kernel_launch(void* const* d_in, const int* in_sizes, int n_in,
                              void* d_out, int out_size, void* d_ws, size_t ws_size,
                              hipStream_t stream) {
    const float* x   = (const float*)d_in[0];
    const float* mem = (const float*)d_in[1];
    float* out = (float*)d_out;

    _Float16* mem_h  = (_Float16*)d_ws;                  // [512][1024] fp16, 1 MB
    _Float16* memT_h = mem_h + (size_t)DIM * MEMSZ;      // [1024][512] fp16, 1 MB

    prep_kernel<<<2048, 256, 0, stream>>>(mem, mem_h, memT_h);
    fused_kernel<<<16 * 32, 512, 0, stream>>>(x, mem_h, memT_h, out);
}